// Round 1
// baseline (79.447 us; speedup 1.0000x reference)
//
#include <hip/hip_runtime.h>
#include <hip/hip_bf16.h>

// Exclusive prefix sum of degs -> offsets (segment start indices into idxn).
// Single block of 1024 threads; each thread serially sums a contiguous chunk,
// block-level Hillis-Steele scan of chunk sums, then each thread writes its
// chunk's exclusive offsets.
__global__ __launch_bounds__(1024) void scan_degs_kernel(
    const int* __restrict__ degs, int* __restrict__ offsets, int S) {
    const int T = 1024;
    int t = threadIdx.x;
    int chunk = (S + T - 1) / T;
    int begin = t * chunk;
    int end   = begin + chunk; if (end > S) end = S;
    if (begin > S) begin = S;

    int sum = 0;
    for (int i = begin; i < end; ++i) sum += degs[i];

    __shared__ int tmp[T];
    tmp[t] = sum;
    __syncthreads();
    int val = sum;
    for (int off = 1; off < T; off <<= 1) {
        int add = (t >= off) ? tmp[t - off] : 0;
        __syncthreads();
        val += add;
        tmp[t] = val;
        __syncthreads();
    }
    // val = inclusive scan of chunk sums; exclusive base for this chunk:
    int run = val - sum;
    for (int i = begin; i < end; ++i) {
        offsets[i] = run;
        run += degs[i];
    }
}

// One block per segment. 256 threads = 8 edge-groups x 32 lanes.
// Lane c4 reads float4 #c4 of each row (rows are 128 floats = 32 float4),
// group j handles edges j, j+8, j+16, ... -> 8 coalesced 512B row reads in
// flight per block. LDS-combine the 8 partials, divide by deg, write out.
__global__ __launch_bounds__(256) void seg_mean_kernel(
    const float* __restrict__ input,
    const int*   __restrict__ idxn,
    const int*   __restrict__ offsets,     // may be null -> binary search
    const int*   __restrict__ seg_ids,     // sorted segment id per edge
    const int*   __restrict__ degs,
    float*       __restrict__ out,
    int E, int S) {
    int s   = blockIdx.x;
    int tid = threadIdx.x;
    int c4  = tid & 31;   // float4 index within the 128-float row
    int j   = tid >> 5;   // edge interleave group, 0..7

    int deg = degs[s];
    int start;
    if (offsets != nullptr) {
        start = offsets[s];
    } else {
        // first index with seg_ids[idx] >= s (seg_ids sorted ascending)
        int lo = 0, hi = E;
        while (lo < hi) {
            int mid = (lo + hi) >> 1;
            if (seg_ids[mid] < s) lo = mid + 1; else hi = mid;
        }
        start = lo;
    }

    const float4* __restrict__ in4 = (const float4*)input;
    float4 acc = make_float4(0.f, 0.f, 0.f, 0.f);
    for (int e = j; e < deg; e += 8) {
        int row = idxn[start + e];
        float4 v = in4[(size_t)row * 32 + c4];
        acc.x += v.x; acc.y += v.y; acc.z += v.z; acc.w += v.w;
    }

    __shared__ float4 sbuf[8][32];
    sbuf[j][c4] = acc;
    __syncthreads();

    if (tid < 32) {
        float4 t = sbuf[0][c4];
#pragma unroll
        for (int k = 1; k < 8; ++k) {
            float4 v = sbuf[k][c4];
            t.x += v.x; t.y += v.y; t.z += v.z; t.w += v.w;
        }
        float inv = (deg > 0) ? (1.f / (float)deg) : 0.f;
        t.x *= inv; t.y *= inv; t.z *= inv; t.w *= inv;
        ((float4*)out)[(size_t)s * 32 + c4] = t;
    }
}

extern "C" void kernel_launch(void* const* d_in, const int* in_sizes, int n_in,
                              void* d_out, int out_size, void* d_ws, size_t ws_size,
                              hipStream_t stream) {
    const float* input   = (const float*)d_in[0];
    const int*   idxn    = (const int*)d_in[1];
    const int*   seg_ids = (const int*)d_in[2];
    const int*   degs    = (const int*)d_in[3];
    // d_in[4] = num_segments scalar (unused; S from in_sizes[3])

    int E = in_sizes[1];
    int S = in_sizes[3];
    float* out = (float*)d_out;

    if (ws_size >= (size_t)S * sizeof(int)) {
        int* offsets = (int*)d_ws;
        scan_degs_kernel<<<1, 1024, 0, stream>>>(degs, offsets, S);
        seg_mean_kernel<<<S, 256, 0, stream>>>(input, idxn, offsets, seg_ids,
                                               degs, out, E, S);
    } else {
        // No workspace: per-block binary search on sorted segment_ids.
        seg_mean_kernel<<<S, 256, 0, stream>>>(input, idxn, nullptr, seg_ids,
                                               degs, out, E, S);
    }
}

// Round 2
// 77.234 us; speedup vs baseline: 1.0286x; 1.0286x over previous
//
#include <hip/hip_runtime.h>
#include <hip/hip_bf16.h>

// Exclusive prefix sum of degs -> offsets (segment start indices into idxn).
__global__ __launch_bounds__(1024) void scan_degs_kernel(
    const int* __restrict__ degs, int* __restrict__ offsets, int S) {
    const int T = 1024;
    int t = threadIdx.x;
    int chunk = (S + T - 1) / T;
    int begin = t * chunk;
    int end   = begin + chunk; if (end > S) end = S;
    if (begin > S) begin = S;

    int sum = 0;
    for (int i = begin; i < end; ++i) sum += degs[i];

    __shared__ int tmp[T];
    tmp[t] = sum;
    __syncthreads();
    int val = sum;
    for (int off = 1; off < T; off <<= 1) {
        int add = (t >= off) ? tmp[t - off] : 0;
        __syncthreads();
        val += add;
        tmp[t] = val;
        __syncthreads();
    }
    int run = val - sum;   // exclusive base for this chunk
    for (int i = begin; i < end; ++i) {
        offsets[i] = run;
        run += degs[i];
    }
}

// One block per segment. 256 threads = 8 edge-groups x 32 lanes.
// idxn slice staged to LDS first (kills the dependent global idx load),
// then a 4-deep unrolled gather -> 4 independent 512B row loads in flight
// per thread. LDS-combine partials, divide by deg, coalesced float4 store.
#define NG 8          // edge groups per block
#define MAXD 1024     // idx staging capacity (generic fallback past this)

__global__ __launch_bounds__(256) void seg_mean_kernel(
    const float* __restrict__ input,
    const int*   __restrict__ idxn,
    const int*   __restrict__ offsets,     // may be null -> binary search
    const int*   __restrict__ seg_ids,     // sorted segment id per edge
    const int*   __restrict__ degs,
    float*       __restrict__ out,
    int E, int S) {
    int s   = blockIdx.x;
    int tid = threadIdx.x;
    int c4  = tid & 31;   // float4 index within the 128-float row
    int j   = tid >> 5;   // edge interleave group, 0..NG-1

    int deg = degs[s];
    int start;
    if (offsets != nullptr) {
        start = offsets[s];
    } else {
        int lo = 0, hi = E;
        while (lo < hi) {
            int mid = (lo + hi) >> 1;
            if (seg_ids[mid] < s) lo = mid + 1; else hi = mid;
        }
        start = lo;
    }

    __shared__ int sidx[MAXD];
    int dstage = deg < MAXD ? deg : MAXD;
    for (int e = tid; e < dstage; e += 256) sidx[e] = idxn[start + e];
    __syncthreads();

    const float4* __restrict__ in4 = (const float4*)input;
    float4 a0 = make_float4(0.f,0.f,0.f,0.f);
    float4 a1 = a0, a2 = a0, a3 = a0;

    int e = j;
    // 4-deep: 4 independent row loads in flight
    for (; e + 3*NG < dstage; e += 4*NG) {
        int r0 = sidx[e];
        int r1 = sidx[e +   NG];
        int r2 = sidx[e + 2*NG];
        int r3 = sidx[e + 3*NG];
        float4 v0 = in4[(size_t)r0 * 32 + c4];
        float4 v1 = in4[(size_t)r1 * 32 + c4];
        float4 v2 = in4[(size_t)r2 * 32 + c4];
        float4 v3 = in4[(size_t)r3 * 32 + c4];
        a0.x += v0.x; a0.y += v0.y; a0.z += v0.z; a0.w += v0.w;
        a1.x += v1.x; a1.y += v1.y; a1.z += v1.z; a1.w += v1.w;
        a2.x += v2.x; a2.y += v2.y; a2.z += v2.z; a2.w += v2.w;
        a3.x += v3.x; a3.y += v3.y; a3.z += v3.z; a3.w += v3.w;
    }
    // staged remainder
    for (; e < dstage; e += NG) {
        int r = sidx[e];
        float4 v = in4[(size_t)r * 32 + c4];
        a0.x += v.x; a0.y += v.y; a0.z += v.z; a0.w += v.w;
    }
    // generic tail if deg > MAXD (not expected for this problem)
    for (; e < deg; e += NG) {
        int r = idxn[start + e];
        float4 v = in4[(size_t)r * 32 + c4];
        a0.x += v.x; a0.y += v.y; a0.z += v.z; a0.w += v.w;
    }

    a0.x += a1.x + a2.x + a3.x;
    a0.y += a1.y + a2.y + a3.y;
    a0.z += a1.z + a2.z + a3.z;
    a0.w += a1.w + a2.w + a3.w;

    __shared__ float4 sbuf[NG][32];
    sbuf[j][c4] = a0;
    __syncthreads();

    if (tid < 32) {
        float4 t = sbuf[0][c4];
#pragma unroll
        for (int k = 1; k < NG; ++k) {
            float4 v = sbuf[k][c4];
            t.x += v.x; t.y += v.y; t.z += v.z; t.w += v.w;
        }
        float inv = (deg > 0) ? (1.f / (float)deg) : 0.f;
        t.x *= inv; t.y *= inv; t.z *= inv; t.w *= inv;
        ((float4*)out)[(size_t)s * 32 + c4] = t;
    }
}

extern "C" void kernel_launch(void* const* d_in, const int* in_sizes, int n_in,
                              void* d_out, int out_size, void* d_ws, size_t ws_size,
                              hipStream_t stream) {
    const float* input   = (const float*)d_in[0];
    const int*   idxn    = (const int*)d_in[1];
    const int*   seg_ids = (const int*)d_in[2];
    const int*   degs    = (const int*)d_in[3];

    int E = in_sizes[1];
    int S = in_sizes[3];
    float* out = (float*)d_out;

    if (ws_size >= (size_t)S * sizeof(int)) {
        int* offsets = (int*)d_ws;
        scan_degs_kernel<<<1, 1024, 0, stream>>>(degs, offsets, S);
        seg_mean_kernel<<<S, 256, 0, stream>>>(input, idxn, offsets, seg_ids,
                                               degs, out, E, S);
    } else {
        seg_mean_kernel<<<S, 256, 0, stream>>>(input, idxn, nullptr, seg_ids,
                                               degs, out, E, S);
    }
}